// Round 1
// 493.420 us; speedup vs baseline: 1.2814x; 1.2814x over previous
//
#include <hip/hip_runtime.h>
#include <hip/hip_bf16.h>
#include <stdint.h>

namespace {

constexpr int M = 8192;
constexpr int N = 4096;
constexpr int K = 4096;
constexpr float CLIP = 100.0f;
constexpr float THRESH = 0.5f;

typedef __bf16 bf16x8 __attribute__((ext_vector_type(8)));
typedef __bf16 bf16x4 __attribute__((ext_vector_type(4)));
typedef float f32x4 __attribute__((ext_vector_type(4)));

__device__ __forceinline__ void load16_to_lds(const void* gptr, void* lptr) {
  __builtin_amdgcn_global_load_lds(
      (const __attribute__((address_space(1))) uint32_t*)gptr,
      (__attribute__((address_space(3))) uint32_t*)lptr,
      16, 0, 0);
}

__device__ __forceinline__ __bf16 tern(float w) {
  return (__bf16)((w > THRESH) ? 1.0f : ((w < -THRESH) ? -1.0f : 0.0f));
}

// ---- prep 1: x fp32 -> bf16, row-major, 16B stores ----
__global__ __launch_bounds__(256) void prep_x_kernel(
    const float* __restrict__ x, __bf16* __restrict__ xb) {
  const int total = M * K / 8;
  const int stride = gridDim.x * blockDim.x;
  for (int i = blockIdx.x * blockDim.x + threadIdx.x; i < total; i += stride) {
    const float4 v0 = reinterpret_cast<const float4*>(x)[2 * i];
    const float4 v1 = reinterpret_cast<const float4*>(x)[2 * i + 1];
    bf16x8 c;
    c[0] = (__bf16)v0.x; c[1] = (__bf16)v0.y; c[2] = (__bf16)v0.z; c[3] = (__bf16)v0.w;
    c[4] = (__bf16)v1.x; c[5] = (__bf16)v1.y; c[6] = (__bf16)v1.z; c[7] = (__bf16)v1.w;
    reinterpret_cast<bf16x8*>(xb)[i] = c;
  }
}

// ---- prep 2: W [K][N] fp32 -> ternarize -> transpose -> Wt [N][K] bf16 ----
__global__ __launch_bounds__(256) void prep_w_kernel(
    const float* __restrict__ W, __bf16* __restrict__ Wt) {
  __shared__ __bf16 sT[64][68];
  const int t = threadIdx.x;
  const int k0 = blockIdx.y * 64;
  const int n0 = blockIdx.x * 64;

#pragma unroll
  for (int i = 0; i < 4; ++i) {
    const int k = i * 16 + (t >> 4);
    const int n4 = (t & 15);
    const float4 v = *reinterpret_cast<const float4*>(
        W + (size_t)(k0 + k) * N + n0 + n4 * 4);
    bf16x4 c;
    c[0] = tern(v.x); c[1] = tern(v.y); c[2] = tern(v.z); c[3] = tern(v.w);
    *reinterpret_cast<bf16x4*>(&sT[k][n4 * 4]) = c;
  }
  __syncthreads();
#pragma unroll
  for (int i = 0; i < 4; ++i) {
    const int n = i * 16 + (t >> 4);
    const int k4 = (t & 15);
    bf16x4 c;
#pragma unroll
    for (int cc = 0; cc < 4; ++cc) c[cc] = sT[k4 * 4 + cc][n];
    *reinterpret_cast<bf16x4*>(Wt + (size_t)(n0 + n) * K + k0 + k4 * 4) = c;
  }
}

// ================= main GEMM: 256x256 tile, BK=64, 8-phase counted-vmcnt =================
// LDS: 2 buffers x 4 regions {A_ks0, A_ks1, B_ks0, B_ks1}, region = 256 rows x 32 bf16.
// Region-free ledger (per iteration i, tiles E=2i -> buf0, O=2i+1 -> buf1):
//   P1 reads buf0{Aks0[0-3],Bks0}, stages AK1(O)->buf1   (buf1.AK1 last read prev P8)
//   P2 reads buf0{Aks0[4-7]},      stages BK0(E+2)->buf0 (last read P1)
//   P3 reads buf0{Aks1[0-3],Bks1}, stages AK0(E+2)->buf0 (last read P2)
//   P4 reads buf0{Aks1[4-7]},      stages BK1(E+2)->buf0 (last read P3)   + vmcnt(6)
//   P5 reads buf1{Aks0[0-3],Bks0}, stages AK1(E+2)->buf0 (last read P4)
//   P6 reads buf1{Aks0[4-7]},      stages BK0(O+2)->buf1 (last read P5)
//   P7 reads buf1{Aks1[0-3],Bks1}, stages AK0(O+2)->buf1 (last read P6)
//   P8 reads buf1{Aks1[4-7]},      stages BK1(O+2)->buf1 (last read P7)   + vmcnt(6)
// vmcnt(6) = 3 half-tiles (2 loads/wave each) stay in flight; all data needed by the
// next 4 phases was staged >=4 stage-slots earlier, hence retired.
constexpr int BK = 64;
constexpr int REG_BYTES = 16384;          // 256 rows x 64 B
constexpr int BUF_BYTES = 4 * REG_BYTES;  // 64 KiB per buffer

// Bank-spread swizzle (involution, XORs addr bits 4-5 with row bits 1-2):
// read group becomes (row & 7) -> all 8 four-bank groups covered, 2 lanes each (free).
__device__ __forceinline__ int swz(int x) { return x ^ (((x >> 7) & 3) << 4); }

#define PH_SYNC()                                        \
  do {                                                   \
    __builtin_amdgcn_s_barrier();                        \
    asm volatile("s_waitcnt lgkmcnt(0)" ::: "memory");   \
    __builtin_amdgcn_sched_barrier(0);                   \
  } while (0)

#define PH_MFMA(ro)                                      \
  do {                                                   \
    __builtin_amdgcn_s_setprio(1);                       \
    mfma_block(ro);                                      \
    __builtin_amdgcn_s_setprio(0);                       \
    __builtin_amdgcn_sched_barrier(0);                   \
    __builtin_amdgcn_s_barrier();                        \
  } while (0)

#define PH_MFMA_VM(ro, n)                                \
  do {                                                   \
    __builtin_amdgcn_s_setprio(1);                       \
    mfma_block(ro);                                      \
    __builtin_amdgcn_s_setprio(0);                       \
    asm volatile("s_waitcnt vmcnt(" #n ")" ::: "memory");\
    __builtin_amdgcn_sched_barrier(0);                   \
    __builtin_amdgcn_s_barrier();                        \
  } while (0)

__global__ __launch_bounds__(512, 2) void gemm256_kernel(
    const __bf16* __restrict__ A, const __bf16* __restrict__ Bt,
    const float* __restrict__ scale, const float* __restrict__ bias,
    float* __restrict__ out) {
  __shared__ __attribute__((aligned(16))) char lds[2 * BUF_BYTES];  // 128 KiB

  const int tid  = threadIdx.x;
  const int lane = tid & 63;
  const int w    = tid >> 6;   // wave 0..7
  const int wrow = w >> 2;     // 0..1 (M)
  const int wcol = w & 3;      // 0..3 (N)
  const int l15  = lane & 15;
  const int quad = lane >> 4;

  // XCD-aware block swizzle: 512 blocks, 8 XCDs, 64 per chunk (512 % 8 == 0 -> bijective)
  int bid = blockIdx.x;
  bid = (bid & 7) * 64 + (bid >> 3);
  const int bm = (bid >> 4) * 256;  // 32 M-tiles
  const int bn = (bid & 15) * 256;  // 16 N-tiles

  // ---- staging geometry: per wave, 2 chunks of 1024 B per region ----
  // stored offset p = w*1024 + c*8192 + lane*16 ; logical = swz(p) -> (row, colbyte)
  int st_dst[2];
  const __bf16* a_src[2];
  const __bf16* b_src[2];
#pragma unroll
  for (int c = 0; c < 2; ++c) {
    const int p  = w * 1024 + c * 8192 + lane * 16;
    const int lg = swz(p);
    const int row  = lg >> 6;
    const int colb = lg & 63;
    st_dst[c] = w * 1024 + c * 8192;
    a_src[c] = A  + (size_t)(bm + row) * K + (colb >> 1);
    b_src[c] = Bt + (size_t)(bn + row) * K + (colb >> 1);
  }

  auto stageA = [&](int buf, int h, int k0) {
#pragma unroll
    for (int c = 0; c < 2; ++c)
      load16_to_lds(a_src[c] + k0 + h * 32,
                    &lds[buf * BUF_BYTES + h * REG_BYTES + st_dst[c]]);
  };
  auto stageB = [&](int buf, int h, int k0) {
#pragma unroll
    for (int c = 0; c < 2; ++c)
      load16_to_lds(b_src[c] + k0 + h * 32,
                    &lds[buf * BUF_BYTES + (2 + h) * REG_BYTES + st_dst[c]]);
  };

  // ---- fragment LDS offsets (loop-invariant, swizzled) ----
  int aoff[8], boff[4];
#pragma unroll
  for (int i = 0; i < 8; ++i) {
    const int row = wrow * 128 + i * 16 + l15;
    aoff[i] = swz(row * 64 + quad * 16);
  }
#pragma unroll
  for (int j = 0; j < 4; ++j) {
    const int row = wcol * 64 + j * 16 + l15;
    boff[j] = swz(row * 64 + quad * 16);
  }

  f32x4 acc[8][4] = {};
  bf16x8 aF[4], bF[4];

  auto rdA4 = [&](int buf, int ks, int i0) {
#pragma unroll
    for (int i = 0; i < 4; ++i)
      aF[i] = *reinterpret_cast<const bf16x8*>(
          &lds[buf * BUF_BYTES + ks * REG_BYTES + aoff[i0 + i]]);
  };
  auto rdB4 = [&](int buf, int ks) {
#pragma unroll
    for (int j = 0; j < 4; ++j)
      bF[j] = *reinterpret_cast<const bf16x8*>(
          &lds[buf * BUF_BYTES + (2 + ks) * REG_BYTES + boff[j]]);
  };
  auto mfma_block = [&](int ro) {
#pragma unroll
    for (int i = 0; i < 4; ++i)
#pragma unroll
      for (int j = 0; j < 4; ++j)
        acc[ro + i][j] = __builtin_amdgcn_mfma_f32_16x16x32_bf16(
            aF[i], bF[j], acc[ro + i][j], 0, 0, 0);
  };

  // ---- prologue: tile0 fully + tile1 {BK0, AK0, BK1} (AK1(t1) staged at first P1) ----
  stageA(0, 0, 0);
  stageB(0, 0, 0);
  stageA(0, 1, 0);
  stageB(0, 1, 0);
  stageB(1, 0, BK);
  stageA(1, 0, BK);
  stageB(1, 1, BK);
  asm volatile("s_waitcnt vmcnt(6)" ::: "memory");  // tile0's 8 loads retired
  __builtin_amdgcn_sched_barrier(0);
  __builtin_amdgcn_s_barrier();

  // ---- main loop: 31 iterations, tiles 0..61; tiles 62,63 handled in epilogue ----
  for (int k2 = 0; k2 + 2 * BK < K; k2 += 2 * BK) {
    const int kO  = k2 + BK;
    const int kE2 = k2 + 2 * BK;
    const int kO2 = k2 + 3 * BK;
    // P1
    rdA4(0, 0, 0); rdB4(0, 0);
    stageA(1, 1, kO);
    PH_SYNC(); PH_MFMA(0);
    // P2
    rdA4(0, 0, 4);
    stageB(0, 0, kE2);
    PH_SYNC(); PH_MFMA(4);
    // P3
    rdA4(0, 1, 0); rdB4(0, 1);
    stageA(0, 0, kE2);
    PH_SYNC(); PH_MFMA(0);
    // P4
    rdA4(0, 1, 4);
    stageB(0, 1, kE2);
    PH_SYNC(); PH_MFMA_VM(4, 6);
    // P5
    rdA4(1, 0, 0); rdB4(1, 0);
    stageA(0, 1, kE2);
    PH_SYNC(); PH_MFMA(0);
    // P6
    rdA4(1, 0, 4);
    stageB(1, 0, kO2);
    PH_SYNC(); PH_MFMA(4);
    // P7
    rdA4(1, 1, 0); rdB4(1, 1);
    stageA(1, 0, kO2);
    PH_SYNC(); PH_MFMA(0);
    // P8
    rdA4(1, 1, 4);
    stageB(1, 1, kO2);
    PH_SYNC(); PH_MFMA_VM(4, 6);
  }

  // ---- epilogue tiles: 62 (buf0, fully staged), 63 (buf1, AK1 missing) ----
  stageA(1, 1, K - BK);  // AK1(63); buf1.AK1 last read at final P8
  // tile 62
  rdA4(0, 0, 0); rdB4(0, 0); PH_SYNC(); PH_MFMA(0);
  rdA4(0, 0, 4);             PH_SYNC(); PH_MFMA(4);
  rdA4(0, 1, 0); rdB4(0, 1); PH_SYNC(); PH_MFMA(0);
  rdA4(0, 1, 4);             PH_SYNC(); PH_MFMA_VM(4, 0);  // drain: tile63 complete
  // tile 63
  rdA4(1, 0, 0); rdB4(1, 0); PH_SYNC(); PH_MFMA(0);
  rdA4(1, 0, 4);             PH_SYNC(); PH_MFMA(4);
  rdA4(1, 1, 0); rdB4(1, 1); PH_SYNC(); PH_MFMA(0);
  rdA4(1, 1, 4);             PH_SYNC(); PH_MFMA(4);

  // ---- output: scale, bias, clip; C/D layout col=lane&15, row=quad*4+reg ----
#pragma unroll
  for (int j = 0; j < 4; ++j) {
    const int n = bn + wcol * 64 + j * 16 + l15;
    const float s = scale[n];
    const float b = bias[n];
#pragma unroll
    for (int i = 0; i < 8; ++i) {
#pragma unroll
      for (int r = 0; r < 4; ++r) {
        const int m = bm + wrow * 128 + i * 16 + quad * 4 + r;
        float v = acc[i][j][r] * s + b;
        v = fminf(fmaxf(v, -CLIP), CLIP);
        out[(size_t)m * N + n] = v;
      }
    }
  }
}

// ================= fallback (ws too small): fused 128-tile kernel =================
constexpr int LDA = 40;
constexpr int LDB = 40;

__global__ __launch_bounds__(256) void ternary_gemm_fallback(
    const float* __restrict__ x, const float* __restrict__ W,
    const float* __restrict__ scale, const float* __restrict__ bias,
    float* __restrict__ out) {
  __shared__ __bf16 sA[128 * LDA];
  __shared__ __bf16 sB[128 * LDB];

  const int tid  = threadIdx.x;
  const int lane = tid & 63;
  const int wave = tid >> 6;
  const int wm   = (wave >> 1) * 64;
  const int wn   = (wave & 1) * 64;
  const int l15  = lane & 15;
  const int quad = lane >> 4;
  const int bm = blockIdx.y * 128;
  const int bn = blockIdx.x * 128;
  const int a_row = tid >> 3;
  const int a_c4  = tid & 7;
  const int b_kg = tid >> 5;
  const int b_ng = tid & 31;

  f32x4 acc[4][4] = {};
  for (int k0 = 0; k0 < K; k0 += 32) {
#pragma unroll
    for (int i = 0; i < 4; ++i) {
      const int row = a_row + i * 32;
      const float4 v = *reinterpret_cast<const float4*>(
          x + (size_t)(bm + row) * K + k0 + a_c4 * 4);
      bf16x4 c;
      c[0] = (__bf16)v.x; c[1] = (__bf16)v.y; c[2] = (__bf16)v.z; c[3] = (__bf16)v.w;
      *reinterpret_cast<bf16x4*>(&sA[row * LDA + a_c4 * 4]) = c;
    }
    {
      __bf16 t[4][4];
#pragma unroll
      for (int j = 0; j < 4; ++j) {
        const float4 v = *reinterpret_cast<const float4*>(
            W + (size_t)(k0 + b_kg * 4 + j) * N + bn + b_ng * 4);
        t[j][0] = tern(v.x); t[j][1] = tern(v.y); t[j][2] = tern(v.z); t[j][3] = tern(v.w);
      }
#pragma unroll
      for (int c = 0; c < 4; ++c) {
        bf16x4 col;
        col[0] = t[0][c]; col[1] = t[1][c]; col[2] = t[2][c]; col[3] = t[3][c];
        *reinterpret_cast<bf16x4*>(&sB[(b_ng * 4 + c) * LDB + b_kg * 4]) = col;
      }
    }
    __syncthreads();
    bf16x8 af[4], bfr[4];
#pragma unroll
    for (int i = 0; i < 4; ++i)
      af[i] = *reinterpret_cast<const bf16x8*>(&sA[(wm + i * 16 + l15) * LDA + quad * 8]);
#pragma unroll
    for (int j = 0; j < 4; ++j)
      bfr[j] = *reinterpret_cast<const bf16x8*>(&sB[(wn + j * 16 + l15) * LDB + quad * 8]);
#pragma unroll
    for (int i = 0; i < 4; ++i)
#pragma unroll
      for (int j = 0; j < 4; ++j)
        acc[i][j] = __builtin_amdgcn_mfma_f32_16x16x32_bf16(af[i], bfr[j], acc[i][j], 0, 0, 0);
    __syncthreads();
  }
#pragma unroll
  for (int j = 0; j < 4; ++j) {
    const int n = bn + wn + j * 16 + l15;
    const float s = scale[n];
    const float b = bias[n];
#pragma unroll
    for (int i = 0; i < 4; ++i)
#pragma unroll
      for (int r = 0; r < 4; ++r) {
        const int m = bm + wm + i * 16 + quad * 4 + r;
        float v = acc[i][j][r] * s + b;
        v = fminf(fmaxf(v, -CLIP), CLIP);
        out[(size_t)m * N + n] = v;
      }
  }
}

}  // namespace

extern "C" void kernel_launch(void* const* d_in, const int* in_sizes, int n_in,
                              void* d_out, int out_size, void* d_ws, size_t ws_size,
                              hipStream_t stream) {
  const float* x     = (const float*)d_in[0];
  const float* W     = (const float*)d_in[1];
  const float* scale = (const float*)d_in[2];
  const float* bias  = (const float*)d_in[3];
  float* out = (float*)d_out;

  const size_t xb_bytes = (size_t)M * K * sizeof(__bf16);   // 67.1 MB
  const size_t wt_bytes = (size_t)N * K * sizeof(__bf16);   // 33.5 MB

  if (ws_size >= xb_bytes + wt_bytes) {
    __bf16* xb = (__bf16*)d_ws;
    __bf16* wt = (__bf16*)((char*)d_ws + xb_bytes);
    prep_x_kernel<<<2048, 256, 0, stream>>>(x, xb);
    prep_w_kernel<<<dim3(N / 64, K / 64), 256, 0, stream>>>(W, wt);
    gemm256_kernel<<<dim3((M / 256) * (N / 256)), 512, 0, stream>>>(xb, wt, scale, bias, out);
  } else {
    ternary_gemm_fallback<<<dim3(N / 128, M / 128), 256, 0, stream>>>(x, W, scale, bias, out);
  }
}

// Round 3
// 481.742 us; speedup vs baseline: 1.3124x; 1.0242x over previous
//
#include <hip/hip_runtime.h>
#include <hip/hip_bf16.h>
#include <stdint.h>

namespace {

constexpr int M = 8192;
constexpr int N = 4096;
constexpr int K = 4096;
constexpr float CLIP = 100.0f;
constexpr float THRESH = 0.5f;

typedef __bf16 bf16x8 __attribute__((ext_vector_type(8)));
typedef __bf16 bf16x4 __attribute__((ext_vector_type(4)));
typedef float f32x4 __attribute__((ext_vector_type(4)));

__device__ __forceinline__ void load16_to_lds(const void* gptr, void* lptr) {
  __builtin_amdgcn_global_load_lds(
      (const __attribute__((address_space(1))) uint32_t*)gptr,
      (__attribute__((address_space(3))) uint32_t*)lptr,
      16, 0, 0);
}

__device__ __forceinline__ __bf16 tern(float w) {
  return (__bf16)((w > THRESH) ? 1.0f : ((w < -THRESH) ? -1.0f : 0.0f));
}

// ---- fused prep: blocks [0,2048) convert x fp32->bf16; blocks [2048,6144) ternarize+transpose W ----
__global__ __launch_bounds__(256) void prep_fused_kernel(
    const float* __restrict__ x, __bf16* __restrict__ xb,
    const float* __restrict__ W, __bf16* __restrict__ Wt) {
  __shared__ __bf16 sT[64][68];

  if (blockIdx.x < 2048) {
    const int total = M * K / 8;
    const int stride = 2048 * 256;
    for (int i = blockIdx.x * 256 + threadIdx.x; i < total; i += stride) {
      const float4 v0 = reinterpret_cast<const float4*>(x)[2 * i];
      const float4 v1 = reinterpret_cast<const float4*>(x)[2 * i + 1];
      bf16x8 c;
      c[0] = (__bf16)v0.x; c[1] = (__bf16)v0.y; c[2] = (__bf16)v0.z; c[3] = (__bf16)v0.w;
      c[4] = (__bf16)v1.x; c[5] = (__bf16)v1.y; c[6] = (__bf16)v1.z; c[7] = (__bf16)v1.w;
      reinterpret_cast<bf16x8*>(xb)[i] = c;
    }
  } else {
    const int wb = blockIdx.x - 2048;   // 0..4095
    const int t = threadIdx.x;
    const int n0 = (wb & 63) * 64;      // N/64 == 64
    const int k0 = (wb >> 6) * 64;      // K/64 == 64

#pragma unroll
    for (int i = 0; i < 4; ++i) {
      const int k = i * 16 + (t >> 4);
      const int n4 = (t & 15);
      const float4 v = *reinterpret_cast<const float4*>(
          W + (size_t)(k0 + k) * N + n0 + n4 * 4);
      bf16x4 c;
      c[0] = tern(v.x); c[1] = tern(v.y); c[2] = tern(v.z); c[3] = tern(v.w);
      *reinterpret_cast<bf16x4*>(&sT[k][n4 * 4]) = c;
    }
    __syncthreads();
#pragma unroll
    for (int i = 0; i < 4; ++i) {
      const int n = i * 16 + (t >> 4);
      const int k4 = (t & 15);
      bf16x4 c;
#pragma unroll
      for (int cc = 0; cc < 4; ++cc) c[cc] = sT[k4 * 4 + cc][n];
      *reinterpret_cast<bf16x4*>(Wt + (size_t)(n0 + n) * K + k0 + k4 * 4) = c;
    }
  }
}

// ================= main GEMM: 256x256 tile, BK=64, 8-phase counted-vmcnt =================
// LDS: 2 buffers x 4 regions {A_ks0, A_ks1, B_ks0, B_ks1}, region = 256 rows x 32 bf16.
// Region-free ledger (per iteration i, tiles E=2i -> buf0, O=2i+1 -> buf1):
//   P1 reads buf0{Aks0[0-3],Bks0}, stages AK1(O)->buf1   (buf1.AK1 last read prev P8)
//   P2 reads buf0{Aks0[4-7]},      stages BK0(E+2)->buf0 (last read P1)
//   P3 reads buf0{Aks1[0-3],Bks1}, stages AK0(E+2)->buf0 (last read P2)
//   P4 reads buf0{Aks1[4-7]},      stages BK1(E+2)->buf0 (last read P3)   + vmcnt(6)
//   P5 reads buf1{Aks0[0-3],Bks0}, stages AK1(E+2)->buf0 (last read P4)
//   P6 reads buf1{Aks0[4-7]},      stages BK0(O+2)->buf1 (last read P5)
//   P7 reads buf1{Aks1[0-3],Bks1}, stages AK0(O+2)->buf1 (last read P6)
//   P8 reads buf1{Aks1[4-7]},      stages BK1(O+2)->buf1 (last read P7)   + vmcnt(6)
// vmcnt(6) = 3 half-tiles (2 loads/wave each) stay in flight.
constexpr int BK = 64;
constexpr int REG_BYTES = 16384;          // 256 rows x 64 B
constexpr int BUF_BYTES = 4 * REG_BYTES;  // 64 KiB per buffer

// Bank-spread swizzle (involution, XORs addr bits 4-5 with row bits 1-2).
__device__ __forceinline__ int swz(int x) { return x ^ (((x >> 7) & 3) << 4); }

#define PH_SYNC()                                        \
  do {                                                   \
    __builtin_amdgcn_s_barrier();                        \
    asm volatile("s_waitcnt lgkmcnt(0)" ::: "memory");   \
    __builtin_amdgcn_sched_barrier(0);                   \
  } while (0)

#define PH_MFMA(ro)                                      \
  do {                                                   \
    __builtin_amdgcn_s_setprio(1);                       \
    mfma_block(ro);                                      \
    __builtin_amdgcn_s_setprio(0);                       \
    __builtin_amdgcn_sched_barrier(0);                   \
    __builtin_amdgcn_s_barrier();                        \
  } while (0)

#define PH_MFMA_VM(ro, n)                                \
  do {                                                   \
    __builtin_amdgcn_s_setprio(1);                       \
    mfma_block(ro);                                      \
    __builtin_amdgcn_s_setprio(0);                       \
    asm volatile("s_waitcnt vmcnt(" #n ")" ::: "memory");\
    __builtin_amdgcn_sched_barrier(0);                   \
    __builtin_amdgcn_s_barrier();                        \
  } while (0)

__global__ __launch_bounds__(512, 2) void gemm256_kernel(
    const __bf16* __restrict__ A, const __bf16* __restrict__ Bt,
    const float* __restrict__ scale, const float* __restrict__ bias,
    float* __restrict__ out) {
  __shared__ __attribute__((aligned(16))) char lds[2 * BUF_BYTES];  // 128 KiB

  const int tid  = threadIdx.x;
  const int lane = tid & 63;
  const int w    = tid >> 6;   // wave 0..7
  const int wrow = w >> 2;     // 0..1 (M)
  const int wcol = w & 3;      // 0..3 (N)
  const int l15  = lane & 15;
  const int quad = lane >> 4;

  // XCD-aware block swizzle: 512 blocks, 8 XCDs, 64 per chunk (bijective since 512%8==0)
  int bid = blockIdx.x;
  bid = (bid & 7) * 64 + (bid >> 3);
  const int bm = (bid >> 4) * 256;  // 32 M-tiles
  const int bn = (bid & 15) * 256;  // 16 N-tiles

  // ---- staging geometry: per wave, 2 chunks of 1024 B per region ----
  int st_dst[2];
  const __bf16* a_src[2];
  const __bf16* b_src[2];
#pragma unroll
  for (int c = 0; c < 2; ++c) {
    const int p  = w * 1024 + c * 8192 + lane * 16;
    const int lg = swz(p);
    const int row  = lg >> 6;
    const int colb = lg & 63;
    st_dst[c] = w * 1024 + c * 8192;
    a_src[c] = A  + (size_t)(bm + row) * K + (colb >> 1);
    b_src[c] = Bt + (size_t)(bn + row) * K + (colb >> 1);
  }

  auto stageA = [&](int buf, int h, int k0) {
#pragma unroll
    for (int c = 0; c < 2; ++c)
      load16_to_lds(a_src[c] + k0 + h * 32,
                    &lds[buf * BUF_BYTES + h * REG_BYTES + st_dst[c]]);
  };
  auto stageB = [&](int buf, int h, int k0) {
#pragma unroll
    for (int c = 0; c < 2; ++c)
      load16_to_lds(b_src[c] + k0 + h * 32,
                    &lds[buf * BUF_BYTES + (2 + h) * REG_BYTES + st_dst[c]]);
  };

  // ---- fragment LDS offsets (loop-invariant, swizzled) ----
  int aoff[8], boff[4];
#pragma unroll
  for (int i = 0; i < 8; ++i) {
    const int row = wrow * 128 + i * 16 + l15;
    aoff[i] = swz(row * 64 + quad * 16);
  }
#pragma unroll
  for (int j = 0; j < 4; ++j) {
    const int row = wcol * 64 + j * 16 + l15;
    boff[j] = swz(row * 64 + quad * 16);
  }

  f32x4 acc[8][4] = {};
  bf16x8 aF[4], bF[4];

  auto rdA4 = [&](int buf, int ks, int i0) {
#pragma unroll
    for (int i = 0; i < 4; ++i)
      aF[i] = *reinterpret_cast<const bf16x8*>(
          &lds[buf * BUF_BYTES + ks * REG_BYTES + aoff[i0 + i]]);
  };
  auto rdB4 = [&](int buf, int ks) {
#pragma unroll
    for (int j = 0; j < 4; ++j)
      bF[j] = *reinterpret_cast<const bf16x8*>(
          &lds[buf * BUF_BYTES + (2 + ks) * REG_BYTES + boff[j]]);
  };
  auto mfma_block = [&](int ro) {
#pragma unroll
    for (int i = 0; i < 4; ++i)
#pragma unroll
      for (int j = 0; j < 4; ++j)
        acc[ro + i][j] = __builtin_amdgcn_mfma_f32_16x16x32_bf16(
            aF[i], bF[j], acc[ro + i][j], 0, 0, 0);
  };

  // ---- prologue: tile0 fully + tile1 {BK0, AK0, BK1} ----
  stageA(0, 0, 0);
  stageB(0, 0, 0);
  stageA(0, 1, 0);
  stageB(0, 1, 0);
  stageB(1, 0, BK);
  stageA(1, 0, BK);
  stageB(1, 1, BK);
  asm volatile("s_waitcnt vmcnt(6)" ::: "memory");  // tile0's 8 loads retired
  __builtin_amdgcn_sched_barrier(0);
  __builtin_amdgcn_s_barrier();

  // ---- main loop: tiles 0..61; tiles 62,63 in epilogue ----
  for (int k2 = 0; k2 + 2 * BK < K; k2 += 2 * BK) {
    const int kO  = k2 + BK;
    const int kE2 = k2 + 2 * BK;
    const int kO2 = k2 + 3 * BK;
    // P1
    rdA4(0, 0, 0); rdB4(0, 0);
    stageA(1, 1, kO);
    PH_SYNC(); PH_MFMA(0);
    // P2
    rdA4(0, 0, 4);
    stageB(0, 0, kE2);
    PH_SYNC(); PH_MFMA(4);
    // P3
    rdA4(0, 1, 0); rdB4(0, 1);
    stageA(0, 0, kE2);
    PH_SYNC(); PH_MFMA(0);
    // P4
    rdA4(0, 1, 4);
    stageB(0, 1, kE2);
    PH_SYNC(); PH_MFMA_VM(4, 6);
    // P5
    rdA4(1, 0, 0); rdB4(1, 0);
    stageA(0, 1, kE2);
    PH_SYNC(); PH_MFMA(0);
    // P6
    rdA4(1, 0, 4);
    stageB(1, 0, kO2);
    PH_SYNC(); PH_MFMA(4);
    // P7
    rdA4(1, 1, 0); rdB4(1, 1);
    stageA(1, 0, kO2);
    PH_SYNC(); PH_MFMA(0);
    // P8
    rdA4(1, 1, 4);
    stageB(1, 1, kO2);
    PH_SYNC(); PH_MFMA_VM(4, 6);
  }

  // ---- epilogue tiles: 62 (buf0 fully staged), 63 (buf1, AK1 missing) ----
  stageA(1, 1, K - BK);  // AK1(63)
  rdA4(0, 0, 0); rdB4(0, 0); PH_SYNC(); PH_MFMA(0);
  rdA4(0, 0, 4);             PH_SYNC(); PH_MFMA(4);
  rdA4(0, 1, 0); rdB4(0, 1); PH_SYNC(); PH_MFMA(0);
  rdA4(0, 1, 4);             PH_SYNC(); PH_MFMA_VM(4, 0);  // drain: tile63 complete
  rdA4(1, 0, 0); rdB4(1, 0); PH_SYNC(); PH_MFMA(0);
  rdA4(1, 0, 4);             PH_SYNC(); PH_MFMA(4);
  rdA4(1, 1, 0); rdB4(1, 1); PH_SYNC(); PH_MFMA(0);
  rdA4(1, 1, 4);             PH_SYNC(); PH_MFMA(4);

  // Full fence+barrier before reusing staging LDS for the C-tile: unlike the raw
  // s_barrier in PH_MFMA, __syncthreads() orders all prior LDS reads against the
  // upcoming per-wave ds_writes (closes the cross-wave reuse race).
  __syncthreads();

  // ---- C-write: per-wave LDS staging -> fully-coalesced f32x4 nontemporal stores ----
  // C/D layout: col = lane&15, row = quad*4 + reg. Wave tile = 128 rows x 64 cols.
  float* cbuf = reinterpret_cast<float*>(&lds[w * 16384]);  // 16 KiB = 64x64 f32
  const int baseM = bm + wrow * 128;
  const int baseN = bn + wcol * 64;
  float sv[4], bv[4];
#pragma unroll
  for (int j = 0; j < 4; ++j) {
    sv[j] = scale[baseN + j * 16 + l15];
    bv[j] = bias[baseN + j * 16 + l15];
  }
#pragma unroll
  for (int h = 0; h < 2; ++h) {
#pragma unroll
    for (int i = 0; i < 4; ++i) {
      const int ii = h * 4 + i;
#pragma unroll
      for (int j = 0; j < 4; ++j) {
#pragma unroll
        for (int r = 0; r < 4; ++r) {
          float v = acc[ii][j][r] * sv[j] + bv[j];
          v = fminf(fmaxf(v, -CLIP), CLIP);
          cbuf[(i * 16 + quad * 4 + r) * 64 + j * 16 + l15] = v;
        }
      }
    }
    // read back contiguous rows: 64 lanes cover 4 rows x 64 cols per pass
#pragma unroll
    for (int g = 0; g < 16; ++g) {
      const int row = g * 4 + quad;
      const f32x4 v = *reinterpret_cast<const f32x4*>(&cbuf[row * 64 + l15 * 4]);
      __builtin_nontemporal_store(
          v, reinterpret_cast<f32x4*>(out + (size_t)(baseM + h * 64 + row) * N +
                                      baseN + l15 * 4));
    }
  }
}

// ================= fallback (ws too small): fused 128-tile kernel =================
constexpr int LDA = 40;
constexpr int LDB = 40;

__global__ __launch_bounds__(256) void ternary_gemm_fallback(
    const float* __restrict__ x, const float* __restrict__ W,
    const float* __restrict__ scale, const float* __restrict__ bias,
    float* __restrict__ out) {
  __shared__ __bf16 sA[128 * LDA];
  __shared__ __bf16 sB[128 * LDB];

  const int tid  = threadIdx.x;
  const int lane = tid & 63;
  const int wave = tid >> 6;
  const int wm   = (wave >> 1) * 64;
  const int wn   = (wave & 1) * 64;
  const int l15  = lane & 15;
  const int quad = lane >> 4;
  const int bm = blockIdx.y * 128;
  const int bn = blockIdx.x * 128;
  const int a_row = tid >> 3;
  const int a_c4  = tid & 7;
  const int b_kg = tid >> 5;
  const int b_ng = tid & 31;

  f32x4 acc[4][4] = {};
  for (int k0 = 0; k0 < K; k0 += 32) {
#pragma unroll
    for (int i = 0; i < 4; ++i) {
      const int row = a_row + i * 32;
      const float4 v = *reinterpret_cast<const float4*>(
          x + (size_t)(bm + row) * K + k0 + a_c4 * 4);
      bf16x4 c;
      c[0] = (__bf16)v.x; c[1] = (__bf16)v.y; c[2] = (__bf16)v.z; c[3] = (__bf16)v.w;
      *reinterpret_cast<bf16x4*>(&sA[row * LDA + a_c4 * 4]) = c;
    }
    {
      __bf16 t[4][4];
#pragma unroll
      for (int j = 0; j < 4; ++j) {
        const float4 v = *reinterpret_cast<const float4*>(
            W + (size_t)(k0 + b_kg * 4 + j) * N + bn + b_ng * 4);
        t[j][0] = tern(v.x); t[j][1] = tern(v.y); t[j][2] = tern(v.z); t[j][3] = tern(v.w);
      }
#pragma unroll
      for (int c = 0; c < 4; ++c) {
        bf16x4 col;
        col[0] = t[0][c]; col[1] = t[1][c]; col[2] = t[2][c]; col[3] = t[3][c];
        *reinterpret_cast<bf16x4*>(&sB[(b_ng * 4 + c) * LDB + b_kg * 4]) = col;
      }
    }
    __syncthreads();
    bf16x8 af[4], bfr[4];
#pragma unroll
    for (int i = 0; i < 4; ++i)
      af[i] = *reinterpret_cast<const bf16x8*>(&sA[(wm + i * 16 + l15) * LDA + quad * 8]);
#pragma unroll
    for (int j = 0; j < 4; ++j)
      bfr[j] = *reinterpret_cast<const bf16x8*>(&sB[(wn + j * 16 + l15) * LDB + quad * 8]);
#pragma unroll
    for (int i = 0; i < 4; ++i)
#pragma unroll
      for (int j = 0; j < 4; ++j)
        acc[i][j] = __builtin_amdgcn_mfma_f32_16x16x32_bf16(af[i], bfr[j], acc[i][j], 0, 0, 0);
    __syncthreads();
  }
#pragma unroll
  for (int j = 0; j < 4; ++j) {
    const int n = bn + wn + j * 16 + l15;
    const float s = scale[n];
    const float b = bias[n];
#pragma unroll
    for (int i = 0; i < 4; ++i)
#pragma unroll
      for (int r = 0; r < 4; ++r) {
        const int m = bm + wm + i * 16 + quad * 4 + r;
        float v = acc[i][j][r] * s + b;
        v = fminf(fmaxf(v, -CLIP), CLIP);
        out[(size_t)m * N + n] = v;
      }
  }
}

}  // namespace

extern "C" void kernel_launch(void* const* d_in, const int* in_sizes, int n_in,
                              void* d_out, int out_size, void* d_ws, size_t ws_size,
                              hipStream_t stream) {
  const float* x     = (const float*)d_in[0];
  const float* W     = (const float*)d_in[1];
  const float* scale = (const float*)d_in[2];
  const float* bias  = (const float*)d_in[3];
  float* out = (float*)d_out;

  const size_t xb_bytes = (size_t)M * K * sizeof(__bf16);   // 67.1 MB
  const size_t wt_bytes = (size_t)N * K * sizeof(__bf16);   // 33.5 MB

  if (ws_size >= xb_bytes + wt_bytes) {
    __bf16* xb = (__bf16*)d_ws;
    __bf16* wt = (__bf16*)((char*)d_ws + xb_bytes);
    prep_fused_kernel<<<6144, 256, 0, stream>>>(x, xb, W, wt);
    gemm256_kernel<<<dim3((M / 256) * (N / 256)), 512, 0, stream>>>(xb, wt, scale, bias, out);
  } else {
    ternary_gemm_fallback<<<dim3(N / 128, M / 128), 256, 0, stream>>>(x, W, scale, bias, out);
  }
}